// Round 1
// baseline (4353.989 us; speedup 1.0000x reference)
//
#include <hip/hip_runtime.h>
#include <math.h>

#define B_ 8192
#define H_ 1024
#define ZD 16
#define LDP 136   // padded LDS stride for 32x128 tiles (16B-aligned: 136*4=544)
#define TSP 36    // padded stride for Ts chunk (36*4=144, 16B-aligned)

__device__ __forceinline__ float sigf(float x){ return 1.0f/(1.0f+__expf(-x)); }
__device__ __forceinline__ float splus(float x){
  return fmaxf(x,0.0f) + __logf(1.0f + __expf(-fabsf(x)));
}

// ---------------- K1: a1 = x @ W1 + b1  (B x H) ----------------
__global__ void k1_a1(const float* __restrict__ x, const float* __restrict__ W1,
                      const float* __restrict__ b1, float* __restrict__ a1){
  __shared__ float xs[ZD];
  int b = blockIdx.x, t = threadIdx.x;
  if(t < ZD) xs[t] = x[b*ZD + t];
  __syncthreads();
  for(int h = t; h < H_; h += 256){
    float acc = b1[h];
    #pragma unroll
    for(int j=0;j<ZD;j++) acc += xs[j]*W1[j*H_ + h];
    a1[b*H_ + h] = acc;
  }
}

// ---------------- K2: a2 = softplus(a1) @ W2 + b2 ----------------
__global__ __launch_bounds__(256,3) void k2_a2(const float* __restrict__ a1,
                      const float* __restrict__ W2, const float* __restrict__ b2,
                      float* __restrict__ a2){
  __shared__ __align__(16) float As[32*LDP];
  __shared__ __align__(16) float Bs[32*LDP];
  int t = threadIdx.x, tx = t & 15, ty = t >> 4;
  int m0 = blockIdx.x * 128, n0 = blockIdx.y * 128;
  int jj = t & 31, rb4 = (t >> 5) * 4;
  float acc[8][8];
  #pragma unroll
  for(int i=0;i<8;i++){ 
    #pragma unroll
    for(int k=0;k<8;k++) acc[i][k]=0.f; }

  for(int jt=0; jt<32; jt++){
    int j0 = jt*32;
    __syncthreads();
    #pragma unroll
    for(int g=0; g<4; g++){
      #pragma unroll
      for(int i=0;i<4;i++){
        int r = rb4 + i + 32*g;
        As[jj*LDP + r] = splus(a1[(m0+r)*H_ + j0 + jj]);
      }
    }
    { int jB = t >> 3, kb = (t & 7) * 16;
      const float* src = &W2[(j0 + jB)*H_ + n0 + kb];
      #pragma unroll
      for(int c=0;c<4;c++) *(float4*)&Bs[jB*LDP + kb + 4*c] = *(const float4*)(src + 4*c);
    }
    __syncthreads();
    #pragma unroll 8
    for(int j=0;j<32;j++){
      float4 a0 = *(const float4*)&As[j*LDP + 8*ty];
      float4 a1f= *(const float4*)&As[j*LDP + 8*ty+4];
      float4 b0 = *(const float4*)&Bs[j*LDP + 4*tx];
      float4 b1f= *(const float4*)&Bs[j*LDP + 64 + 4*tx];
      float aa[8] = {a0.x,a0.y,a0.z,a0.w,a1f.x,a1f.y,a1f.z,a1f.w};
      float bb[8] = {b0.x,b0.y,b0.z,b0.w,b1f.x,b1f.y,b1f.z,b1f.w};
      #pragma unroll
      for(int i=0;i<8;i++){
        #pragma unroll
        for(int k=0;k<8;k++) acc[i][k] += aa[i]*bb[k]; }
    }
  }
  float4 bb0 = *(const float4*)&b2[n0 + 4*tx];
  float4 bb1 = *(const float4*)&b2[n0 + 64 + 4*tx];
  #pragma unroll
  for(int i=0;i<8;i++){
    int r = m0 + 8*ty + i;
    float4 o0 = make_float4(acc[i][0]+bb0.x, acc[i][1]+bb0.y, acc[i][2]+bb0.z, acc[i][3]+bb0.w);
    float4 o1 = make_float4(acc[i][4]+bb1.x, acc[i][5]+bb1.y, acc[i][6]+bb1.z, acc[i][7]+bb1.w);
    *(float4*)&a2[r*H_ + n0 + 4*tx] = o0;
    *(float4*)&a2[r*H_ + n0 + 64 + 4*tx] = o1;
  }
}

// ---------------- K3: u = (w3*sigmoid(a2)) @ W2^T ----------------
__global__ __launch_bounds__(256,3) void k3_u(const float* __restrict__ a2,
                      const float* __restrict__ W2, const float* __restrict__ W3,
                      float* __restrict__ u){
  __shared__ __align__(16) float As[32*LDP];
  __shared__ __align__(16) float Bs[32*LDP];
  int t = threadIdx.x, tx = t & 15, ty = t >> 4;
  int m0 = blockIdx.x * 128, n0 = blockIdx.y * 128;  // n0: output j-cols
  int jj = t & 31, rb4 = (t >> 5) * 4;
  float acc[8][8];
  #pragma unroll
  for(int i=0;i<8;i++){ 
    #pragma unroll
    for(int k=0;k<8;k++) acc[i][k]=0.f; }

  for(int kt=0; kt<32; kt++){
    int k0 = kt*32;
    __syncthreads();
    float w3v = W3[k0 + jj];
    #pragma unroll
    for(int g=0; g<4; g++){
      #pragma unroll
      for(int i=0;i<4;i++){
        int r = rb4 + i + 32*g;
        As[jj*LDP + r] = w3v * sigf(a2[(m0+r)*H_ + k0 + jj]);
      }
    }
    { // B^T stage: Bs[kk][jcol] = W2[n0+jcol][k0+kk]
      int jcol = t >> 1, kb = (t & 1) * 16;
      const float* src = &W2[(n0 + jcol)*H_ + k0 + kb];
      #pragma unroll
      for(int c=0;c<16;c++) Bs[(kb+c)*LDP + jcol] = src[c];
    }
    __syncthreads();
    #pragma unroll 8
    for(int j=0;j<32;j++){
      float4 a0 = *(const float4*)&As[j*LDP + 8*ty];
      float4 a1f= *(const float4*)&As[j*LDP + 8*ty+4];
      float4 b0 = *(const float4*)&Bs[j*LDP + 4*tx];
      float4 b1f= *(const float4*)&Bs[j*LDP + 64 + 4*tx];
      float aa[8] = {a0.x,a0.y,a0.z,a0.w,a1f.x,a1f.y,a1f.z,a1f.w};
      float bb[8] = {b0.x,b0.y,b0.z,b0.w,b1f.x,b1f.y,b1f.z,b1f.w};
      #pragma unroll
      for(int i=0;i<8;i++){
        #pragma unroll
        for(int k=0;k<8;k++) acc[i][k] += aa[i]*bb[k]; }
    }
  }
  #pragma unroll
  for(int i=0;i<8;i++){
    int r = m0 + 8*ty + i;
    *(float4*)&u[r*H_ + n0 + 4*tx]      = make_float4(acc[i][0],acc[i][1],acc[i][2],acc[i][3]);
    *(float4*)&u[r*H_ + n0 + 64 + 4*tx] = make_float4(acc[i][4],acc[i][5],acc[i][6],acc[i][7]);
  }
}

// ---------------- K0: F[j][p] = W1[8+(p>>4)][j] * W1[p&15][j] ----------------
__global__ void k0_F(const float* __restrict__ W1, float* __restrict__ F){
  int e = blockIdx.x*256 + threadIdx.x;
  int j = e >> 7, p = e & 127;
  F[e] = W1[(8+(p>>4))*H_ + j] * W1[(p&15)*H_ + j];
}

// ---------------- K5a: Hz1 = D1 @ F   (D1 = s1(1-s1)*u) ----------------
__global__ __launch_bounds__(256) void k5a(const float* __restrict__ a1,
                      const float* __restrict__ u, const float* __restrict__ F,
                      float* __restrict__ Hz1){
  __shared__ __align__(16) float As[32*72];
  __shared__ __align__(16) float Bs[32*72];
  int t = threadIdx.x, tx = t & 15, ty = t >> 4;
  int m0 = blockIdx.x * 64, n0 = blockIdx.y * 64;
  int jj = t & 31, rb8 = (t >> 5) * 8;
  float acc[4][4];
  #pragma unroll
  for(int i=0;i<4;i++){ 
    #pragma unroll
    for(int k=0;k<4;k++) acc[i][k]=0.f; }

  for(int jt=0; jt<32; jt++){
    int j0 = jt*32;
    __syncthreads();
    #pragma unroll
    for(int g=0; g<8; g++){
      int r = rb8 + g;
      float s = sigf(a1[(m0+r)*H_ + j0 + jj]);
      As[jj*72 + r] = s*(1.0f-s)*u[(m0+r)*H_ + j0 + jj];
    }
    { int jB = t >> 3, cb = (t & 7) * 8;
      const float* src = &F[(j0 + jB)*128 + n0 + cb];
      *(float4*)&Bs[jB*72 + cb]   = *(const float4*)(src);
      *(float4*)&Bs[jB*72 + cb+4] = *(const float4*)(src+4);
    }
    __syncthreads();
    #pragma unroll 8
    for(int j=0;j<32;j++){
      float4 a4 = *(const float4*)&As[j*72 + 4*ty];
      float4 b4 = *(const float4*)&Bs[j*72 + 4*tx];
      float aa[4] = {a4.x,a4.y,a4.z,a4.w};
      float bb[4] = {b4.x,b4.y,b4.z,b4.w};
      #pragma unroll
      for(int i=0;i<4;i++){
        #pragma unroll
        for(int k=0;k<4;k++) acc[i][k] += aa[i]*bb[k]; }
    }
  }
  #pragma unroll
  for(int i=0;i<4;i++)
    *(float4*)&Hz1[(m0+4*ty+i)*128 + n0 + 4*tx] =
      make_float4(acc[i][0],acc[i][1],acc[i][2],acc[i][3]);
}

// ---------------- K5b: dLdq[b][i] = sum_j W1[i][j]*s1*u, i<8 ----------------
__global__ void k5b(const float* __restrict__ a1, const float* __restrict__ u,
                    const float* __restrict__ W1, float* __restrict__ dLdq){
  int wid = threadIdx.x >> 6, lane = threadIdx.x & 63;
  int b = blockIdx.x*4 + wid;
  float acc[8] = {0,0,0,0,0,0,0,0};
  for(int jb=0;jb<16;jb++){
    int j = jb*64 + lane;
    float g1 = sigf(a1[b*H_+j]) * u[b*H_+j];
    #pragma unroll
    for(int i=0;i<8;i++) acc[i] += g1*W1[i*H_+j];
  }
  #pragma unroll
  for(int i=0;i<8;i++){
    #pragma unroll
    for(int off=32; off; off>>=1) acc[i] += __shfl_down(acc[i], off);
  }
  if(lane==0){
    #pragma unroll
    for(int i=0;i<8;i++) dLdq[b*8+i] = acc[i];
  }
}

// ---------------- K4: Hz2 (the 275 GFLOP kernel) ----------------
// Per block: 8 samples. T = (W1 .* s1) @ W2 computed tile-wise (128 rows x 128 k),
// contracted against diag(d2) chunk-wise through LDS (never hits HBM).
__global__ __launch_bounds__(256,3) void k4_hz2(
    const float* __restrict__ a1, const float* __restrict__ a2,
    const float* __restrict__ W1, const float* __restrict__ W2,
    const float* __restrict__ W3, float* __restrict__ Hz2){
  __shared__ __align__(16) float smem[2*32*LDP];   // As | Bs, overlaid by Ts
  __shared__ __align__(16) float d2s[8*128];
  float* As = smem;
  float* Bs = smem + 32*LDP;
  float* Ts = smem;   // 128*36 = 4608 floats <= 8704

  int t = threadIdx.x, tx = t & 15, ty = t >> 4;
  int b0 = blockIdx.x * 8;
  int jj = t & 31, rb4 = (t >> 5) * 4;

  float hz[4] = {0,0,0,0};
  int es  = t >> 5;            // epilogue sample
  int ep0 = (t & 31) * 4;      // pair base: p = (m-8)*16 + n
  int em  = 8 + (ep0 >> 4);
  int en0 = ep0 & 15;

  for(int kt=0; kt<8; kt++){
    int k0 = kt*128;
    float acc[8][8];
    #pragma unroll
    for(int i=0;i<8;i++){ 
      #pragma unroll
      for(int k=0;k<8;k++) acc[i][k]=0.f; }

    for(int jt=0; jt<32; jt++){
      int j0 = jt*32;
      __syncthreads();
      // A: As[jj][r] = W1[m][j]*sigmoid(a1[b0+s][j]),  r = s*16+m
      #pragma unroll
      for(int g=0; g<4; g++){
        int s = (rb4 >> 4) + 2*g;
        float sg = sigf(a1[(b0+s)*H_ + j0 + jj]);
        #pragma unroll
        for(int i=0;i<4;i++){
          int m = (rb4 & 15) + i;
          As[jj*LDP + (s*16+m)] = W1[m*H_ + j0 + jj] * sg;
        }
      }
      { int jB = t >> 3, kb = (t & 7) * 16;
        const float* src = &W2[(j0 + jB)*H_ + k0 + kb];
        #pragma unroll
        for(int c=0;c<4;c++) *(float4*)&Bs[jB*LDP + kb + 4*c] = *(const float4*)(src + 4*c);
      }
      __syncthreads();
      #pragma unroll 8
      for(int j=0;j<32;j++){
        float4 a0 = *(const float4*)&As[j*LDP + 8*ty];
        float4 a1f= *(const float4*)&As[j*LDP + 8*ty+4];
        float4 b0 = *(const float4*)&Bs[j*LDP + 4*tx];
        float4 b1f= *(const float4*)&Bs[j*LDP + 64 + 4*tx];
        float aa[8] = {a0.x,a0.y,a0.z,a0.w,a1f.x,a1f.y,a1f.z,a1f.w};
        float bb[8] = {b0.x,b0.y,b0.z,b0.w,b1f.x,b1f.y,b1f.z,b1f.w};
        #pragma unroll
        for(int i=0;i<8;i++){
          #pragma unroll
          for(int k=0;k<8;k++) acc[i][k] += aa[i]*bb[k]; }
      }
    }
    __syncthreads();   // GEMM reads done; safe to stage d2 and overlay Ts
    { // d2s[s][kk] = w3[k]*s2*(1-s2)
      int e = t*4, s = e>>7, kk = e&127;
      float4 av = *(const float4*)&a2[(b0+s)*H_ + k0 + kk];
      float4 wv = *(const float4*)&W3[k0 + kk];
      float s0=sigf(av.x), s1=sigf(av.y), s2v=sigf(av.z), s3=sigf(av.w);
      *(float4*)&d2s[s*128 + kk] = make_float4(wv.x*s0*(1.f-s0), wv.y*s1*(1.f-s1),
                                               wv.z*s2v*(1.f-s2v), wv.w*s3*(1.f-s3));
    }
    // contract in 4 chunks of 32 k-columns
    #pragma unroll
    for(int c=0;c<4;c++){
      __syncthreads();
      if(((tx>>3)&1) == (c&1)){
        int colbase = 4*(tx&7);
        int half = c>>1;
        #pragma unroll
        for(int i=0;i<8;i++){
          float4 v = half ? make_float4(acc[i][4],acc[i][5],acc[i][6],acc[i][7])
                          : make_float4(acc[i][0],acc[i][1],acc[i][2],acc[i][3]);
          *(float4*)&Ts[(8*ty+i)*TSP + colbase] = v;
        }
      }
      __syncthreads();
      #pragma unroll 4
      for(int k=0;k<32;k++){
        float d  = d2s[es*128 + c*32 + k];
        float tm = Ts[(es*16+em)*TSP + k];
        float w  = tm*d;
        hz[0] += w * Ts[(es*16+en0+0)*TSP + k];
        hz[1] += w * Ts[(es*16+en0+1)*TSP + k];
        hz[2] += w * Ts[(es*16+en0+2)*TSP + k];
        hz[3] += w * Ts[(es*16+en0+3)*TSP + k];
      }
    }
  }
  *(float4*)&Hz2[(b0+es)*128 + ep0] = make_float4(hz[0],hz[1],hz[2],hz[3]);
}

// ---------------- K6: assemble M,C, r; f64 solve; write [qd, qdd] ----------------
__global__ __launch_bounds__(64) void k6(const float* __restrict__ x,
                    const float* __restrict__ Hz1, const float* __restrict__ Hz2,
                    const float* __restrict__ dLdq, float* __restrict__ out){
  __shared__ double A[64][73];
  int t = threadIdx.x;
  int b = blockIdx.x*64 + t;
  double* Ar = A[t];
  float qd[8];
  #pragma unroll
  for(int j=0;j<8;j++) qd[j] = x[b*16 + 8 + j];
  #pragma unroll
  for(int i=0;i<8;i++){
    double r = (double)dLdq[b*8+i];
    #pragma unroll
    for(int j=0;j<8;j++){
      int pM = i*16 + 8 + j;
      int pC = i*16 + j;
      Ar[i*9 + j] = (double)Hz1[b*128+pM] + (double)Hz2[b*128+pM];
      r -= ((double)Hz1[b*128+pC] + (double)Hz2[b*128+pC]) * (double)qd[j];
    }
    Ar[i*9 + 8] = r;
  }
  for(int c=0;c<8;c++){
    int piv = c; double best = fabs(Ar[c*9+c]);
    for(int rr=c+1; rr<8; rr++){ double v = fabs(Ar[rr*9+c]); if(v>best){best=v;piv=rr;} }
    if(piv!=c){
      for(int cc=c; cc<9; cc++){ double tmp=Ar[c*9+cc]; Ar[c*9+cc]=Ar[piv*9+cc]; Ar[piv*9+cc]=tmp; }
    }
    double inv = 1.0/Ar[c*9+c];
    for(int rr=c+1; rr<8; rr++){
      double f = Ar[rr*9+c]*inv;
      for(int cc=c+1; cc<9; cc++) Ar[rr*9+cc] -= f*Ar[c*9+cc];
    }
  }
  double sol[8];
  #pragma unroll
  for(int i=7;i>=0;i--){
    double s = Ar[i*9+8];
    #pragma unroll
    for(int j=i+1;j<8;j++) s -= Ar[i*9+j]*sol[j];
    sol[i] = s/Ar[i*9+i];
  }
  #pragma unroll
  for(int j=0;j<8;j++) out[b*16+j] = qd[j];
  #pragma unroll
  for(int i=0;i<8;i++) out[b*16+8+i] = (float)sol[i];
}

extern "C" void kernel_launch(void* const* d_in, const int* in_sizes, int n_in,
                              void* d_out, int out_size, void* d_ws, size_t ws_size,
                              hipStream_t stream){
  const float* x  = (const float*)d_in[0];
  const float* W1 = (const float*)d_in[1];
  const float* b1 = (const float*)d_in[2];
  const float* W2 = (const float*)d_in[3];
  const float* b2 = (const float*)d_in[4];
  const float* W3 = (const float*)d_in[5];
  float* out = (float*)d_out;

  float* ws   = (float*)d_ws;
  float* a1   = ws;                          // B*H
  float* a2   = a1  + (size_t)B_*H_;         // B*H
  float* u    = a2  + (size_t)B_*H_;         // B*H
  float* F    = u   + (size_t)B_*H_;         // H*128
  float* Hz1  = F   + (size_t)H_*128;        // B*128
  float* Hz2  = Hz1 + (size_t)B_*128;        // B*128
  float* dLdq = Hz2 + (size_t)B_*128;        // B*8

  k1_a1 <<<dim3(B_),    dim3(256), 0, stream>>>(x, W1, b1, a1);
  k2_a2 <<<dim3(64,8),  dim3(256), 0, stream>>>(a1, W2, b2, a2);
  k3_u  <<<dim3(64,8),  dim3(256), 0, stream>>>(a2, W2, W3, u);
  k0_F  <<<dim3(512),   dim3(256), 0, stream>>>(W1, F);
  k5a   <<<dim3(128,2), dim3(256), 0, stream>>>(a1, u, F, Hz1);
  k5b   <<<dim3(2048),  dim3(256), 0, stream>>>(a1, u, W1, dLdq);
  k4_hz2<<<dim3(1024),  dim3(256), 0, stream>>>(a1, a2, W1, W2, W3, Hz2);
  k6    <<<dim3(128),   dim3(64),  0, stream>>>(x, Hz1, Hz2, dLdq, out);
}

// Round 2
// 2626.134 us; speedup vs baseline: 1.6579x; 1.6579x over previous
//
#include <hip/hip_runtime.h>
#include <math.h>

#define B_ 8192
#define H_ 1024
#define LDP0 136   // k2/k3 stride (32-row tiles)
#define LDP 132    // k4 stride: 132%32=4 -> conflict-free b128, 16B aligned

__device__ __forceinline__ float sigf(float x){ return 1.0f/(1.0f+__expf(-x)); }

// ---------------- K1: s1 = sigmoid(x @ W1 + b1)  (B x H) ----------------
__global__ void k1_s1(const float* __restrict__ x, const float* __restrict__ W1,
                      const float* __restrict__ b1, float* __restrict__ s1o){
  __shared__ float xs[16];
  int b = blockIdx.x, t = threadIdx.x;
  if(t < 16) xs[t] = x[b*16 + t];
  __syncthreads();
  for(int h = t; h < H_; h += 256){
    float acc = b1[h];
    #pragma unroll
    for(int j=0;j<16;j++) acc += xs[j]*W1[j*H_ + h];
    s1o[(size_t)b*H_ + h] = sigf(acc);
  }
}

// ---------------- K2: s2 = sigmoid(softplus(a1) @ W2 + b2), softplus = -log(1-s1) ----
__global__ __launch_bounds__(256,3) void k2_s2(const float* __restrict__ s1,
                      const float* __restrict__ W2, const float* __restrict__ b2,
                      float* __restrict__ s2o){
  __shared__ __align__(16) float As[32*LDP0];
  __shared__ __align__(16) float Bs[32*LDP0];
  int t = threadIdx.x, tx = t & 15, ty = t >> 4;
  int m0 = blockIdx.x * 128, n0 = blockIdx.y * 128;
  int jj = t & 31, rb4 = (t >> 5) * 4;
  float acc[8][8];
  #pragma unroll
  for(int i=0;i<8;i++){
    #pragma unroll
    for(int k=0;k<8;k++) acc[i][k]=0.f; }

  for(int jt=0; jt<32; jt++){
    int j0 = jt*32;
    __syncthreads();
    #pragma unroll
    for(int g=0; g<4; g++){
      #pragma unroll
      for(int i=0;i<4;i++){
        int r = rb4 + i + 32*g;
        As[jj*LDP0 + r] = -__logf(1.0f - s1[(size_t)(m0+r)*H_ + j0 + jj]);
      }
    }
    { int jB = t >> 3, kb = (t & 7) * 16;
      const float* src = &W2[(size_t)(j0 + jB)*H_ + n0 + kb];
      #pragma unroll
      for(int c=0;c<4;c++) *(float4*)&Bs[jB*LDP0 + kb + 4*c] = *(const float4*)(src + 4*c);
    }
    __syncthreads();
    #pragma unroll 8
    for(int j=0;j<32;j++){
      float4 a0 = *(const float4*)&As[j*LDP0 + 8*ty];
      float4 a1f= *(const float4*)&As[j*LDP0 + 8*ty+4];
      float4 b0 = *(const float4*)&Bs[j*LDP0 + 4*tx];
      float4 b1f= *(const float4*)&Bs[j*LDP0 + 64 + 4*tx];
      float aa[8] = {a0.x,a0.y,a0.z,a0.w,a1f.x,a1f.y,a1f.z,a1f.w};
      float bb[8] = {b0.x,b0.y,b0.z,b0.w,b1f.x,b1f.y,b1f.z,b1f.w};
      #pragma unroll
      for(int i=0;i<8;i++){
        #pragma unroll
        for(int k=0;k<8;k++) acc[i][k] += aa[i]*bb[k]; }
    }
  }
  float4 bb0 = *(const float4*)&b2[n0 + 4*tx];
  float4 bb1 = *(const float4*)&b2[n0 + 64 + 4*tx];
  #pragma unroll
  for(int i=0;i<8;i++){
    size_t r = (size_t)(m0 + 8*ty + i)*H_;
    float4 o0 = make_float4(sigf(acc[i][0]+bb0.x), sigf(acc[i][1]+bb0.y),
                            sigf(acc[i][2]+bb0.z), sigf(acc[i][3]+bb0.w));
    float4 o1 = make_float4(sigf(acc[i][4]+bb1.x), sigf(acc[i][5]+bb1.y),
                            sigf(acc[i][6]+bb1.z), sigf(acc[i][7]+bb1.w));
    *(float4*)&s2o[r + n0 + 4*tx] = o0;
    *(float4*)&s2o[r + n0 + 64 + 4*tx] = o1;
  }
}

// ---------------- K3: u = (w3*s2) @ W2^T ----------------
__global__ __launch_bounds__(256,3) void k3_u(const float* __restrict__ s2,
                      const float* __restrict__ W2, const float* __restrict__ W3,
                      float* __restrict__ u){
  __shared__ __align__(16) float As[32*LDP0];
  __shared__ __align__(16) float Bs[32*LDP0];
  int t = threadIdx.x, tx = t & 15, ty = t >> 4;
  int m0 = blockIdx.x * 128, n0 = blockIdx.y * 128;
  int jj = t & 31, rb4 = (t >> 5) * 4;
  float acc[8][8];
  #pragma unroll
  for(int i=0;i<8;i++){
    #pragma unroll
    for(int k=0;k<8;k++) acc[i][k]=0.f; }

  for(int kt=0; kt<32; kt++){
    int k0 = kt*32;
    __syncthreads();
    float w3v = W3[k0 + jj];
    #pragma unroll
    for(int g=0; g<4; g++){
      #pragma unroll
      for(int i=0;i<4;i++){
        int r = rb4 + i + 32*g;
        As[jj*LDP0 + r] = w3v * s2[(size_t)(m0+r)*H_ + k0 + jj];
      }
    }
    { int jcol = t >> 1, kb = (t & 1) * 16;
      const float* src = &W2[(size_t)(n0 + jcol)*H_ + k0 + kb];
      #pragma unroll
      for(int c=0;c<16;c++) Bs[(kb+c)*LDP0 + jcol] = src[c];
    }
    __syncthreads();
    #pragma unroll 8
    for(int j=0;j<32;j++){
      float4 a0 = *(const float4*)&As[j*LDP0 + 8*ty];
      float4 a1f= *(const float4*)&As[j*LDP0 + 8*ty+4];
      float4 b0 = *(const float4*)&Bs[j*LDP0 + 4*tx];
      float4 b1f= *(const float4*)&Bs[j*LDP0 + 64 + 4*tx];
      float aa[8] = {a0.x,a0.y,a0.z,a0.w,a1f.x,a1f.y,a1f.z,a1f.w};
      float bb[8] = {b0.x,b0.y,b0.z,b0.w,b1f.x,b1f.y,b1f.z,b1f.w};
      #pragma unroll
      for(int i=0;i<8;i++){
        #pragma unroll
        for(int k=0;k<8;k++) acc[i][k] += aa[i]*bb[k]; }
    }
  }
  #pragma unroll
  for(int i=0;i<8;i++){
    size_t r = (size_t)(m0 + 8*ty + i)*H_;
    *(float4*)&u[r + n0 + 4*tx]      = make_float4(acc[i][0],acc[i][1],acc[i][2],acc[i][3]);
    *(float4*)&u[r + n0 + 64 + 4*tx] = make_float4(acc[i][4],acc[i][5],acc[i][6],acc[i][7]);
  }
}

// ---------------- KF: F64[j][p] = W1[8+(p>>3)][j]*W1[8+(p&7)][j] ----------------
__global__ void kF(const float* __restrict__ W1, float* __restrict__ F64){
  int e = blockIdx.x*256 + threadIdx.x;   // < H*64
  int j = e >> 6, p = e & 63;
  F64[e] = W1[(8+(p>>3))*H_ + j] * W1[(8+(p&7))*H_ + j];
}

// ---------------- K5a: Hz1M = D1 @ F64   (B x 64), D1 = s1(1-s1)u ----------------
__global__ __launch_bounds__(256) void k5a(const float* __restrict__ s1,
                      const float* __restrict__ u, const float* __restrict__ F64,
                      float* __restrict__ Hz1M){
  __shared__ __align__(16) float As[32*72];
  __shared__ __align__(16) float Bs[32*72];
  int t = threadIdx.x, tx = t & 15, ty = t >> 4;
  int m0 = blockIdx.x * 64;
  int jj = t & 31, rb8 = (t >> 5) * 8;
  float acc[4][4];
  #pragma unroll
  for(int i=0;i<4;i++){
    #pragma unroll
    for(int k=0;k<4;k++) acc[i][k]=0.f; }

  for(int jt=0; jt<32; jt++){
    int j0 = jt*32;
    __syncthreads();
    #pragma unroll
    for(int g=0; g<8; g++){
      int r = rb8 + g;
      float s = s1[(size_t)(m0+r)*H_ + j0 + jj];
      As[jj*72 + r] = s*(1.0f-s)*u[(size_t)(m0+r)*H_ + j0 + jj];
    }
    { int jB = t >> 3, cb = (t & 7) * 8;
      const float* src = &F64[(j0 + jB)*64 + cb];
      *(float4*)&Bs[jB*72 + cb]   = *(const float4*)(src);
      *(float4*)&Bs[jB*72 + cb+4] = *(const float4*)(src+4);
    }
    __syncthreads();
    #pragma unroll 8
    for(int j=0;j<32;j++){
      float4 a4 = *(const float4*)&As[j*72 + 4*ty];
      float4 b4 = *(const float4*)&Bs[j*72 + 4*tx];
      float aa[4] = {a4.x,a4.y,a4.z,a4.w};
      float bb[4] = {b4.x,b4.y,b4.z,b4.w};
      #pragma unroll
      for(int i=0;i<4;i++){
        #pragma unroll
        for(int k=0;k<4;k++) acc[i][k] += aa[i]*bb[k]; }
    }
  }
  #pragma unroll
  for(int i=0;i<4;i++)
    *(float4*)&Hz1M[(size_t)(m0+4*ty+i)*64 + 4*tx] =
      make_float4(acc[i][0],acc[i][1],acc[i][2],acc[i][3]);
}

// ---------------- K5b: dq16[b][0:8]=dLdq, [8:16]=c1 ----------------
__global__ void k5b(const float* __restrict__ s1, const float* __restrict__ u,
                    const float* __restrict__ W1, const float* __restrict__ x,
                    float* __restrict__ dq16){
  int wid = threadIdx.x >> 6, lane = threadIdx.x & 63;
  int b = blockIdx.x*4 + wid;
  float qd[8];
  #pragma unroll
  for(int i=0;i<8;i++) qd[i] = x[b*16 + 8 + i];
  float accd[8] = {0,0,0,0,0,0,0,0};
  float accc[8] = {0,0,0,0,0,0,0,0};
  for(int jb=0;jb<16;jb++){
    int j = jb*64 + lane;
    float s1v = s1[(size_t)b*H_+j], uv = u[(size_t)b*H_+j];
    float g1 = s1v*uv;
    float d1 = (1.0f - s1v)*g1;
    float w1q = 0.f;
    #pragma unroll
    for(int i=0;i<8;i++){ float w = W1[i*H_+j]; accd[i] += g1*w; w1q += qd[i]*w; }
    float dw = d1*w1q;
    #pragma unroll
    for(int m=0;m<8;m++) accc[m] += dw * W1[(8+m)*H_+j];
  }
  #pragma unroll
  for(int i=0;i<8;i++){
    #pragma unroll
    for(int off=1; off<64; off<<=1){
      accd[i] += __shfl_xor(accd[i], off, 64);
      accc[i] += __shfl_xor(accc[i], off, 64);
    }
  }
  if(lane==0){
    #pragma unroll
    for(int i=0;i<8;i++){ dq16[b*16+i] = accd[i]; dq16[b*16+8+i] = accc[i]; }
  }
}

// ---------------- K4: Tq = (W1[8:]*s1)@W2, v = (qd.W1[:8]*s1)@W2, contract ----------------
// 16 samples/block; thread (tx,ty) owns sample ty, k-cols {4tx..4tx+3, 64+4tx..+3}.
// M,c accumulate in registers across all kt; shfl-reduce over tx at the end.
__global__ __launch_bounds__(256,2) void k4_hz2(
    const float* __restrict__ s1, const float* __restrict__ s2,
    const float* __restrict__ x,  const float* __restrict__ W1,
    const float* __restrict__ W2, const float* __restrict__ W3,
    float* __restrict__ M2c){
  __shared__ __align__(16) float As[64*LDP];
  __shared__ __align__(16) float Bs[64*LDP];
  __shared__ float Gs[64*17];
  __shared__ float qds[16][8];
  int t = threadIdx.x, tx = t & 15, ty = t >> 4;
  int b0 = blockIdx.x * 16;
  if(t < 128){ int s = t>>3, i = t&7; qds[s][i] = x[(b0+s)*16 + 8 + i]; }

  float Mp[8][8];
  float cp[8];
  #pragma unroll
  for(int m=0;m<8;m++){ cp[m]=0.f;
    #pragma unroll
    for(int n=0;n<8;n++) Mp[m][n]=0.f; }

  int jj = t & 63, sg = t >> 6;

  for(int kt=0; kt<8; kt++){
    int k0 = kt*128;
    float acc[8][8]; float accv[8];
    #pragma unroll
    for(int i=0;i<8;i++){ accv[i]=0.f;
      #pragma unroll
      for(int k=0;k<8;k++) acc[i][k]=0.f; }

    for(int jt=0; jt<16; jt++){
      int j0 = jt*64;
      __syncthreads();
      { // A + G stage: 128 rows x 64 j, plus 16 G-rows
        float w1m[8], w1i[8];
        #pragma unroll
        for(int m=0;m<8;m++){ w1m[m] = W1[(8+m)*H_ + j0+jj]; w1i[m] = W1[m*H_ + j0+jj]; }
        #pragma unroll
        for(int ss=0; ss<4; ss++){
          int s = sg*4 + ss;
          float s1v = s1[(size_t)(b0+s)*H_ + j0+jj];
          float w1q = 0.f;
          #pragma unroll
          for(int i=0;i<8;i++) w1q += qds[s][i]*w1i[i];
          Gs[jj*17 + s] = s1v * w1q;
          float4 v0 = make_float4(w1m[0]*s1v, w1m[1]*s1v, w1m[2]*s1v, w1m[3]*s1v);
          float4 v1 = make_float4(w1m[4]*s1v, w1m[5]*s1v, w1m[6]*s1v, w1m[7]*s1v);
          *(float4*)&As[jj*LDP + s*8]     = v0;
          *(float4*)&As[jj*LDP + s*8 + 4] = v1;
        }
      }
      { // B stage: 64 j-rows x 128 k-cols
        int jB = t >> 2, kb = (t & 3) * 4;
        const float* src = &W2[(size_t)(j0+jB)*H_ + k0 + kb];
        #pragma unroll
        for(int c=0;c<8;c++)
          *(float4*)&Bs[jB*LDP + kb + 16*c] = *(const float4*)(src + 16*c);
      }
      __syncthreads();
      #pragma unroll 4
      for(int j=0;j<64;j++){
        float4 a0 = *(const float4*)&As[j*LDP + 8*ty];
        float4 a1f= *(const float4*)&As[j*LDP + 8*ty + 4];
        float4 b0 = *(const float4*)&Bs[j*LDP + 4*tx];
        float4 b1f= *(const float4*)&Bs[j*LDP + 64 + 4*tx];
        float g  = Gs[j*17 + ty];
        float aa[8] = {a0.x,a0.y,a0.z,a0.w,a1f.x,a1f.y,a1f.z,a1f.w};
        float bb[8] = {b0.x,b0.y,b0.z,b0.w,b1f.x,b1f.y,b1f.z,b1f.w};
        #pragma unroll
        for(int i=0;i<8;i++){
          #pragma unroll
          for(int k=0;k<8;k++) acc[i][k] += aa[i]*bb[k]; }
        #pragma unroll
        for(int k=0;k<8;k++) accv[k] += g*bb[k];
      }
    }
    // per-kt in-register contraction with d2 = w3*s2*(1-s2)
    {
      const float* s2p = &s2[(size_t)(b0+ty)*H_ + k0];
      float4 sa = *(const float4*)&s2p[4*tx];
      float4 sb = *(const float4*)&s2p[64 + 4*tx];
      float4 wa = *(const float4*)&W3[k0 + 4*tx];
      float4 wb = *(const float4*)&W3[k0 + 64 + 4*tx];
      float d2v[8] = { wa.x*sa.x*(1.f-sa.x), wa.y*sa.y*(1.f-sa.y),
                       wa.z*sa.z*(1.f-sa.z), wa.w*sa.w*(1.f-sa.w),
                       wb.x*sb.x*(1.f-sb.x), wb.y*sb.y*(1.f-sb.y),
                       wb.z*sb.z*(1.f-sb.z), wb.w*sb.w*(1.f-sb.w) };
      #pragma unroll
      for(int kk=0;kk<8;kk++){
        float e = d2v[kk]*accv[kk];
        #pragma unroll
        for(int m=0;m<8;m++){
          float w = acc[m][kk]*d2v[kk];
          cp[m] += acc[m][kk]*e;
          #pragma unroll
          for(int n=0;n<8;n++) Mp[m][n] += w*acc[n][kk];
        }
      }
    }
  }
  // reduce across the 16 tx lanes (same ty => consecutive lanes in one wave)
  #pragma unroll
  for(int m=0;m<8;m++){
    #pragma unroll
    for(int n=0;n<8;n++){
      #pragma unroll
      for(int off=1; off<16; off<<=1) Mp[m][n] += __shfl_xor(Mp[m][n], off, 64);
    }
    #pragma unroll
    for(int off=1; off<16; off<<=1) cp[m] += __shfl_xor(cp[m], off, 64);
  }
  if(tx==0){
    float* o = &M2c[(size_t)(b0+ty)*72];
    #pragma unroll
    for(int m=0;m<8;m++){
      #pragma unroll
      for(int n=0;n<8;n++) o[m*8+n] = Mp[m][n];
      o[64+m] = cp[m];
    }
  }
}

// ---------------- K6: A = M1+M2; rhs = dLdq - c1 - c2; f64 solve ----------------
__global__ __launch_bounds__(64) void k6(const float* __restrict__ x,
                    const float* __restrict__ Hz1M, const float* __restrict__ M2c,
                    const float* __restrict__ dq16, float* __restrict__ out){
  __shared__ double A[64][73];
  int t = threadIdx.x;
  int b = blockIdx.x*64 + t;
  double* Ar = A[t];
  float qd[8];
  #pragma unroll
  for(int j=0;j<8;j++) qd[j] = x[b*16 + 8 + j];
  #pragma unroll
  for(int i=0;i<8;i++){
    #pragma unroll
    for(int j=0;j<8;j++)
      Ar[i*9 + j] = (double)Hz1M[(size_t)b*64 + i*8 + j] + (double)M2c[(size_t)b*72 + i*8 + j];
    Ar[i*9 + 8] = (double)dq16[b*16+i] - (double)dq16[b*16+8+i] - (double)M2c[(size_t)b*72 + 64 + i];
  }
  for(int c=0;c<8;c++){
    int piv = c; double best = fabs(Ar[c*9+c]);
    for(int rr=c+1; rr<8; rr++){ double v = fabs(Ar[rr*9+c]); if(v>best){best=v;piv=rr;} }
    if(piv!=c){
      for(int cc=c; cc<9; cc++){ double tmp=Ar[c*9+cc]; Ar[c*9+cc]=Ar[piv*9+cc]; Ar[piv*9+cc]=tmp; }
    }
    double inv = 1.0/Ar[c*9+c];
    for(int rr=c+1; rr<8; rr++){
      double f = Ar[rr*9+c]*inv;
      for(int cc=c+1; cc<9; cc++) Ar[rr*9+cc] -= f*Ar[c*9+cc];
    }
  }
  double sol[8];
  #pragma unroll
  for(int i=7;i>=0;i--){
    double s = Ar[i*9+8];
    #pragma unroll
    for(int j=i+1;j<8;j++) s -= Ar[i*9+j]*sol[j];
    sol[i] = s/Ar[i*9+i];
  }
  #pragma unroll
  for(int j=0;j<8;j++) out[b*16+j] = qd[j];
  #pragma unroll
  for(int i=0;i<8;i++) out[b*16+8+i] = (float)sol[i];
}

extern "C" void kernel_launch(void* const* d_in, const int* in_sizes, int n_in,
                              void* d_out, int out_size, void* d_ws, size_t ws_size,
                              hipStream_t stream){
  const float* x  = (const float*)d_in[0];
  const float* W1 = (const float*)d_in[1];
  const float* b1 = (const float*)d_in[2];
  const float* W2 = (const float*)d_in[3];
  const float* b2 = (const float*)d_in[4];
  const float* W3 = (const float*)d_in[5];
  float* out = (float*)d_out;

  float* ws   = (float*)d_ws;
  float* s1   = ws;                           // B*H
  float* s2   = s1  + (size_t)B_*H_;          // B*H
  float* u    = s2  + (size_t)B_*H_;          // B*H
  float* F64  = u   + (size_t)B_*H_;          // H*64
  float* Hz1M = F64 + (size_t)H_*64;          // B*64
  float* M2c  = Hz1M+ (size_t)B_*64;          // B*72
  float* dq16 = M2c + (size_t)B_*72;          // B*16

  k1_s1 <<<dim3(B_),    dim3(256), 0, stream>>>(x, W1, b1, s1);
  k2_s2 <<<dim3(64,8),  dim3(256), 0, stream>>>(s1, W2, b2, s2);
  k3_u  <<<dim3(64,8),  dim3(256), 0, stream>>>(s2, W2, W3, u);
  kF    <<<dim3(256),   dim3(256), 0, stream>>>(W1, F64);
  k5a   <<<dim3(128),   dim3(256), 0, stream>>>(s1, u, F64, Hz1M);
  k5b   <<<dim3(2048),  dim3(256), 0, stream>>>(s1, u, W1, x, dq16);
  k4_hz2<<<dim3(512),   dim3(256), 0, stream>>>(s1, s2, x, W1, W2, W3, M2c);
  k6    <<<dim3(128),   dim3(64),  0, stream>>>(x, Hz1M, M2c, dq16, out);
}

// Round 4
// 2178.484 us; speedup vs baseline: 1.9986x; 1.2055x over previous
//
#include <hip/hip_runtime.h>
#include <math.h>

#define B_ 8192
#define H_ 1024
#define LDP0 136
#define LDT 148    // Td column stride (floats)
#define ASTR 40    // A-plane row stride (shorts): 80B = 20 banks, 16B-aligned
#define BSTR 40    // B-plane row stride (shorts)

typedef short bfrag __attribute__((ext_vector_type(8)));
typedef float f4v  __attribute__((ext_vector_type(4)));

union U8 { unsigned short u[8]; uint4 v; };

__device__ __forceinline__ float sigf(float x){ return 1.0f/(1.0f+__expf(-x)); }

// pack high halves of two fp32 (bf16-valued) into one u32: [lo16=bf(f0), hi16=bf(f1)]
__device__ __forceinline__ unsigned int pkhi(unsigned int u1, unsigned int u0){
  return __builtin_amdgcn_perm(u1, u0, 0x07060302u);
}

// ---------------- K1: s1 = sigmoid(x @ W1 + b1) ----------------
__global__ void k1_s1(const float* __restrict__ x, const float* __restrict__ W1,
                      const float* __restrict__ b1, float* __restrict__ s1o){
  __shared__ float xs[16];
  int b = blockIdx.x, t = threadIdx.x;
  if(t < 16) xs[t] = x[b*16 + t];
  __syncthreads();
  for(int h = t; h < H_; h += 256){
    float acc = b1[h];
    #pragma unroll
    for(int j=0;j<16;j++) acc += xs[j]*W1[j*H_ + h];
    s1o[(size_t)b*H_ + h] = sigf(acc);
  }
}

// ---------------- K2: s2 = sigmoid(softplus @ W2 + b2), softplus = -log(1-s1) ----
__global__ __launch_bounds__(256,3) void k2_s2(const float* __restrict__ s1,
                      const float* __restrict__ W2, const float* __restrict__ b2,
                      float* __restrict__ s2o){
  __shared__ __align__(16) float As[32*LDP0];
  __shared__ __align__(16) float Bs[32*LDP0];
  int t = threadIdx.x, tx = t & 15, ty = t >> 4;
  int m0 = blockIdx.x * 128, n0 = blockIdx.y * 128;
  int jj = t & 31, rb4 = (t >> 5) * 4;
  float acc[8][8];
  #pragma unroll
  for(int i=0;i<8;i++){
    #pragma unroll
    for(int k=0;k<8;k++) acc[i][k]=0.f; }

  for(int jt=0; jt<32; jt++){
    int j0 = jt*32;
    __syncthreads();
    #pragma unroll
    for(int g=0; g<4; g++){
      #pragma unroll
      for(int i=0;i<4;i++){
        int r = rb4 + i + 32*g;
        As[jj*LDP0 + r] = -__logf(1.0f - s1[(size_t)(m0+r)*H_ + j0 + jj]);
      }
    }
    { int jB = t >> 3, kb = (t & 7) * 16;
      const float* src = &W2[(size_t)(j0 + jB)*H_ + n0 + kb];
      #pragma unroll
      for(int c=0;c<4;c++) *(float4*)&Bs[jB*LDP0 + kb + 4*c] = *(const float4*)(src + 4*c);
    }
    __syncthreads();
    #pragma unroll 8
    for(int j=0;j<32;j++){
      float4 a0 = *(const float4*)&As[j*LDP0 + 8*ty];
      float4 a1f= *(const float4*)&As[j*LDP0 + 8*ty+4];
      float4 b0 = *(const float4*)&Bs[j*LDP0 + 4*tx];
      float4 b1f= *(const float4*)&Bs[j*LDP0 + 64 + 4*tx];
      float aa[8] = {a0.x,a0.y,a0.z,a0.w,a1f.x,a1f.y,a1f.z,a1f.w};
      float bb[8] = {b0.x,b0.y,b0.z,b0.w,b1f.x,b1f.y,b1f.z,b1f.w};
      #pragma unroll
      for(int i=0;i<8;i++){
        #pragma unroll
        for(int k=0;k<8;k++) acc[i][k] += aa[i]*bb[k]; }
    }
  }
  float4 bb0 = *(const float4*)&b2[n0 + 4*tx];
  float4 bb1 = *(const float4*)&b2[n0 + 64 + 4*tx];
  #pragma unroll
  for(int i=0;i<8;i++){
    size_t r = (size_t)(m0 + 8*ty + i)*H_;
    float4 o0 = make_float4(sigf(acc[i][0]+bb0.x), sigf(acc[i][1]+bb0.y),
                            sigf(acc[i][2]+bb0.z), sigf(acc[i][3]+bb0.w));
    float4 o1 = make_float4(sigf(acc[i][4]+bb1.x), sigf(acc[i][5]+bb1.y),
                            sigf(acc[i][6]+bb1.z), sigf(acc[i][7]+bb1.w));
    *(float4*)&s2o[r + n0 + 4*tx] = o0;
    *(float4*)&s2o[r + n0 + 64 + 4*tx] = o1;
  }
}

// ---------------- K3: u = (w3*s2) @ W2^T ----------------
__global__ __launch_bounds__(256,3) void k3_u(const float* __restrict__ s2,
                      const float* __restrict__ W2, const float* __restrict__ W3,
                      float* __restrict__ u){
  __shared__ __align__(16) float As[32*LDP0];
  __shared__ __align__(16) float Bs[32*LDP0];
  int t = threadIdx.x, tx = t & 15, ty = t >> 4;
  int m0 = blockIdx.x * 128, n0 = blockIdx.y * 128;
  int jj = t & 31, rb4 = (t >> 5) * 4;
  float acc[8][8];
  #pragma unroll
  for(int i=0;i<8;i++){
    #pragma unroll
    for(int k=0;k<8;k++) acc[i][k]=0.f; }

  for(int kt=0; kt<32; kt++){
    int k0 = kt*32;
    __syncthreads();
    float w3v = W3[k0 + jj];
    #pragma unroll
    for(int g=0; g<4; g++){
      #pragma unroll
      for(int i=0;i<4;i++){
        int r = rb4 + i + 32*g;
        As[jj*LDP0 + r] = w3v * s2[(size_t)(m0+r)*H_ + k0 + jj];
      }
    }
    { int jcol = t >> 1, kb = (t & 1) * 16;
      const float* src = &W2[(size_t)(n0 + jcol)*H_ + k0 + kb];
      #pragma unroll
      for(int c=0;c<16;c++) Bs[(kb+c)*LDP0 + jcol] = src[c];
    }
    __syncthreads();
    #pragma unroll 8
    for(int j=0;j<32;j++){
      float4 a0 = *(const float4*)&As[j*LDP0 + 8*ty];
      float4 a1f= *(const float4*)&As[j*LDP0 + 8*ty+4];
      float4 b0 = *(const float4*)&Bs[j*LDP0 + 4*tx];
      float4 b1f= *(const float4*)&Bs[j*LDP0 + 64 + 4*tx];
      float aa[8] = {a0.x,a0.y,a0.z,a0.w,a1f.x,a1f.y,a1f.z,a1f.w};
      float bb[8] = {b0.x,b0.y,b0.z,b0.w,b1f.x,b1f.y,b1f.z,b1f.w};
      #pragma unroll
      for(int i=0;i<8;i++){
        #pragma unroll
        for(int k=0;k<8;k++) acc[i][k] += aa[i]*bb[k]; }
    }
  }
  #pragma unroll
  for(int i=0;i<8;i++){
    size_t r = (size_t)(m0 + 8*ty + i)*H_;
    *(float4*)&u[r + n0 + 4*tx]      = make_float4(acc[i][0],acc[i][1],acc[i][2],acc[i][3]);
    *(float4*)&u[r + n0 + 64 + 4*tx] = make_float4(acc[i][4],acc[i][5],acc[i][6],acc[i][7]);
  }
}

// ---------------- KF: F64[j][p] = W1[8+(p>>3)][j]*W1[8+(p&7)][j] ----------------
__global__ void kF(const float* __restrict__ W1, float* __restrict__ F64){
  int e = blockIdx.x*256 + threadIdx.x;
  int j = e >> 6, p = e & 63;
  F64[e] = W1[(8+(p>>3))*H_ + j] * W1[(8+(p&7))*H_ + j];
}

// ---------------- K5a: Hz1M = D1 @ F64 ----------------
__global__ __launch_bounds__(256) void k5a(const float* __restrict__ s1,
                      const float* __restrict__ u, const float* __restrict__ F64,
                      float* __restrict__ Hz1M){
  __shared__ __align__(16) float As[32*72];
  __shared__ __align__(16) float Bs[32*72];
  int t = threadIdx.x, tx = t & 15, ty = t >> 4;
  int m0 = blockIdx.x * 64;
  int jj = t & 31, rb8 = (t >> 5) * 8;
  float acc[4][4];
  #pragma unroll
  for(int i=0;i<4;i++){
    #pragma unroll
    for(int k=0;k<4;k++) acc[i][k]=0.f; }

  for(int jt=0; jt<32; jt++){
    int j0 = jt*32;
    __syncthreads();
    #pragma unroll
    for(int g=0; g<8; g++){
      int r = rb8 + g;
      float s = s1[(size_t)(m0+r)*H_ + j0 + jj];
      As[jj*72 + r] = s*(1.0f-s)*u[(size_t)(m0+r)*H_ + j0 + jj];
    }
    { int jB = t >> 3, cb = (t & 7) * 8;
      const float* src = &F64[(j0 + jB)*64 + cb];
      *(float4*)&Bs[jB*72 + cb]   = *(const float4*)(src);
      *(float4*)&Bs[jB*72 + cb+4] = *(const float4*)(src+4);
    }
    __syncthreads();
    #pragma unroll 8
    for(int j=0;j<32;j++){
      float4 a4 = *(const float4*)&As[j*72 + 4*ty];
      float4 b4 = *(const float4*)&Bs[j*72 + 4*tx];
      float aa[4] = {a4.x,a4.y,a4.z,a4.w};
      float bb[4] = {b4.x,b4.y,b4.z,b4.w};
      #pragma unroll
      for(int i=0;i<4;i++){
        #pragma unroll
        for(int k=0;k<4;k++) acc[i][k] += aa[i]*bb[k]; }
    }
  }
  #pragma unroll
  for(int i=0;i<4;i++)
    *(float4*)&Hz1M[(size_t)(m0+4*ty+i)*64 + 4*tx] =
      make_float4(acc[i][0],acc[i][1],acc[i][2],acc[i][3]);
}

// ---------------- K5b: dq16[b][0:8]=dLdq, [8:16]=c1 ----------------
__global__ void k5b(const float* __restrict__ s1, const float* __restrict__ u,
                    const float* __restrict__ W1, const float* __restrict__ x,
                    float* __restrict__ dq16){
  int wid = threadIdx.x >> 6, lane = threadIdx.x & 63;
  int b = blockIdx.x*4 + wid;
  float qd[8];
  #pragma unroll
  for(int i=0;i<8;i++) qd[i] = x[b*16 + 8 + i];
  float accd[8] = {0,0,0,0,0,0,0,0};
  float accc[8] = {0,0,0,0,0,0,0,0};
  for(int jb=0;jb<16;jb++){
    int j = jb*64 + lane;
    float s1v = s1[(size_t)b*H_+j], uv = u[(size_t)b*H_+j];
    float g1 = s1v*uv;
    float d1 = (1.0f - s1v)*g1;
    float w1q = 0.f;
    #pragma unroll
    for(int i=0;i<8;i++){ float w = W1[i*H_+j]; accd[i] += g1*w; w1q += qd[i]*w; }
    float dw = d1*w1q;
    #pragma unroll
    for(int m=0;m<8;m++) accc[m] += dw * W1[(8+m)*H_+j];
  }
  #pragma unroll
  for(int i=0;i<8;i++){
    #pragma unroll
    for(int off=1; off<64; off<<=1){
      accd[i] += __shfl_xor(accd[i], off, 64);
      accc[i] += __shfl_xor(accc[i], off, 64);
    }
  }
  if(lane==0){
    #pragma unroll
    for(int i=0;i<8;i++){ dq16[b*16+i] = accd[i]; dq16[b*16+8+i] = accc[i]; }
  }
}

// ---------------- KW2T: W2 -> 3 transposed bf16 EXACT-truncation planes [k][j] ----
__global__ void kW2T(const float* __restrict__ W2, unsigned short* __restrict__ Wh,
                     unsigned short* __restrict__ Wm, unsigned short* __restrict__ Wl){
  __shared__ float tile[32][132];
  int j0 = blockIdx.x * 32, k0 = blockIdx.y * 128;
  int t = threadIdx.x;
  int lr = t >> 3, lc0 = (t & 7) * 16;
  const float* src = &W2[(size_t)(j0+lr)*H_ + k0 + lc0];
  #pragma unroll
  for(int c=0;c<16;c+=4) *(float4*)&tile[lr][lc0+c] = *(const float4*)(src + c);
  __syncthreads();
  int k = t >> 1;
  #pragma unroll
  for(int o2=0;o2<2;o2++){
    int oc = (t&1)*2 + o2;
    U8 uh, um2, ul2;
    #pragma unroll
    for(int e=0;e<8;e++){
      float a = tile[oc*8+e][k];
      unsigned int ua = __float_as_uint(a);
      unsigned int h = ua & 0xFFFF0000u;
      float r1 = a - __uint_as_float(h);
      unsigned int m = __float_as_uint(r1) & 0xFFFF0000u;
      float l = r1 - __uint_as_float(m);   // exactly bf16-representable
      uh.u[e]  = (unsigned short)(h >> 16);
      um2.u[e] = (unsigned short)(m >> 16);
      ul2.u[e] = (unsigned short)(__float_as_uint(l) >> 16);
    }
    size_t o = (size_t)(k0+k)*H_ + j0 + oc*8;
    *(uint4*)&Wh[o] = uh.v; *(uint4*)&Wm[o] = um2.v; *(uint4*)&Wl[o] = ul2.v;
  }
}

// ---------------- K4: bf16x8 exact-split MFMA T-GEMM + d2 contraction ----------------
// Block: 16 samples x 128 k-cols. Rows: r<128: T[s=r>>3][m=r&7]; r>=128: G[s=r-128].
// T = A@B with A = W1*s1 split EXACTLY as a0+a1+a2 (truncation), B = W2 likewise.
// 8 MFMA terms (drop only a2*b2 ~ 2^-32). Output Mpart[(b*8+kb)*44]: 36 tri(M) + 8 c2.
__global__ __launch_bounds__(256,2) void k4_mfma(
    const float* __restrict__ s1, const float* __restrict__ s2,
    const float* __restrict__ x,  const float* __restrict__ W1,
    const unsigned short* __restrict__ W2Th, const unsigned short* __restrict__ W2Tm,
    const unsigned short* __restrict__ W2Tl,
    const float* __restrict__ W3, float* __restrict__ Mpart){
  __shared__ union {
    struct { unsigned short A[3][144*ASTR]; unsigned short Bt[3][128*BSTR]; } st;
    float Td[64*LDT];
  } sm;
  __shared__ float qds[16][8];

  int t = threadIdx.x;
  int wv = t >> 6, lane = t & 63;
  int kb = blockIdx.x & 7, sgp = blockIdx.x >> 3;
  int b0 = sgp*16, k0 = kb*128;

  if(t < 128){ int s = t>>3, i = t&7; qds[s][i] = x[(b0+s)*16 + 8+i]; }

  f4v acc[9][2];
  #pragma unroll
  for(int mt=0;mt<9;mt++){
    #pragma unroll
    for(int n2=0;n2<2;n2++){ acc[mt][n2][0]=0.f; acc[mt][n2][1]=0.f; acc[mt][n2][2]=0.f; acc[mt][n2][3]=0.f; }
  }

  int aoct = t & 3, arow = t >> 2;
  int bn = t >> 1;
  int fr_m = lane & 15, fr_q = lane >> 4;

  for(int jt=0; jt<32; jt++){
    int j0 = jt*32;
    __syncthreads();
    // ---- A stage: 144 rows x 32 j, exact 3-way truncation split ----
    #pragma unroll
    for(int pass=0; pass<3; pass++){
      int r = pass*64 + arow;
      if(r < 144){
        float4 w0, w1v, sa, sb;
        if(r < 128){
          int s = r>>3, m = r&7;
          const float* wp = &W1[(size_t)(8+m)*H_ + j0 + aoct*8];
          w0 = *(const float4*)wp; w1v = *(const float4*)(wp+4);
          const float* sp = &s1[(size_t)(b0+s)*H_ + j0 + aoct*8];
          sa = *(const float4*)sp; sb = *(const float4*)(sp+4);
        } else {
          int s = r - 128;
          float g0=0,g1=0,g2=0,g3=0,g4=0,g5=0,g6=0,g7=0;
          #pragma unroll
          for(int i=0;i<8;i++){
            float q = qds[s][i];
            const float* wp = &W1[(size_t)i*H_ + j0 + aoct*8];
            float4 a0 = *(const float4*)wp, a1 = *(const float4*)(wp+4);
            g0 += q*a0.x; g1 += q*a0.y; g2 += q*a0.z; g3 += q*a0.w;
            g4 += q*a1.x; g5 += q*a1.y; g6 += q*a1.z; g7 += q*a1.w;
          }
          w0 = make_float4(g0,g1,g2,g3); w1v = make_float4(g4,g5,g6,g7);
          const float* sp = &s1[(size_t)(b0+s)*H_ + j0 + aoct*8];
          sa = *(const float4*)sp; sb = *(const float4*)(sp+4);
        }
        float av[8];
        av[0]=w0.x*sa.x; av[1]=w0.y*sa.y; av[2]=w0.z*sa.z; av[3]=w0.w*sa.w;
        av[4]=w1v.x*sb.x; av[5]=w1v.y*sb.y; av[6]=w1v.z*sb.z; av[7]=w1v.w*sb.w;
        unsigned int uh[8], um[8], ul[8];
        #pragma unroll
        for(int e=0;e<8;e++){
          unsigned int ua = __float_as_uint(av[e]);
          unsigned int h = ua & 0xFFFF0000u;
          float r1 = av[e] - __uint_as_float(h);
          unsigned int m = __float_as_uint(r1) & 0xFFFF0000u;
          float l = r1 - __uint_as_float(m);   // exact
          uh[e]=h; um[e]=m; ul[e]=__float_as_uint(l);
        }
        int o = r*ASTR + aoct*8;
        uint4 vh = make_uint4(pkhi(uh[1],uh[0]), pkhi(uh[3],uh[2]), pkhi(uh[5],uh[4]), pkhi(uh[7],uh[6]));
        uint4 vm = make_uint4(pkhi(um[1],um[0]), pkhi(um[3],um[2]), pkhi(um[5],um[4]), pkhi(um[7],um[6]));
        uint4 vl = make_uint4(pkhi(ul[1],ul[0]), pkhi(ul[3],ul[2]), pkhi(ul[5],ul[4]), pkhi(ul[7],ul[6]));
        *(uint4*)&sm.st.A[0][o] = vh;
        *(uint4*)&sm.st.A[1][o] = vm;
        *(uint4*)&sm.st.A[2][o] = vl;
      }
    }
    // ---- B stage: 128 n-rows x 32 j, copies from exact pre-split planes ----
    #pragma unroll
    for(int o2=0;o2<2;o2++){
      int oc = (t&1)*2 + o2;
      size_t gsrc = (size_t)(k0+bn)*H_ + j0 + oc*8;
      int o = bn*BSTR + oc*8;
      *(uint4*)&sm.st.Bt[0][o] = *(const uint4*)&W2Th[gsrc];
      *(uint4*)&sm.st.Bt[1][o] = *(const uint4*)&W2Tm[gsrc];
      *(uint4*)&sm.st.Bt[2][o] = *(const uint4*)&W2Tl[gsrc];
    }
    __syncthreads();
    // ---- MFMA: one K=32 step, 8 split-terms, smallest-first ----
    bfrag bf[2][3];
    #pragma unroll
    for(int n2=0;n2<2;n2++){
      int n = (2*wv+n2)*16 + fr_m;
      #pragma unroll
      for(int p=0;p<3;p++) bf[n2][p] = *(bfrag*)&sm.st.Bt[p][n*BSTR + fr_q*8];
    }
    #pragma unroll
    for(int mt=0; mt<9; mt++){
      int rr = mt*16 + fr_m;
      bfrag a0 = *(bfrag*)&sm.st.A[0][rr*ASTR + fr_q*8];
      bfrag a1v= *(bfrag*)&sm.st.A[1][rr*ASTR + fr_q*8];
      bfrag a2v= *(bfrag*)&sm.st.A[2][rr*ASTR + fr_q*8];
      #pragma unroll
      for(int n2=0;n2<2;n2++){
        f4v c = acc[mt][n2];
        c = __builtin_amdgcn_mfma_f32_16x16x32_bf16(a2v, bf[n2][1], c, 0,0,0); // 2^-24
        c = __builtin_amdgcn_mfma_f32_16x16x32_bf16(a1v, bf[n2][2], c, 0,0,0); // 2^-24
        c = __builtin_amdgcn_mfma_f32_16x16x32_bf16(a2v, bf[n2][0], c, 0,0,0); // 2^-16
        c = __builtin_amdgcn_mfma_f32_16x16x32_bf16(a0,  bf[n2][2], c, 0,0,0); // 2^-16
        c = __builtin_amdgcn_mfma_f32_16x16x32_bf16(a1v, bf[n2][1], c, 0,0,0); // 2^-16
        c = __builtin_amdgcn_mfma_f32_16x16x32_bf16(a1v, bf[n2][0], c, 0,0,0); // 2^-8
        c = __builtin_amdgcn_mfma_f32_16x16x32_bf16(a0,  bf[n2][1], c, 0,0,0); // 2^-8
        c = __builtin_amdgcn_mfma_f32_16x16x32_bf16(a0,  bf[n2][0], c, 0,0,0); // 1
        acc[mt][n2] = c;
      }
    }
  }

  // ---- epilogue: 2 phases of (dump 64 cols col-major) + d2 contraction ----
  float Mp[44];
  #pragma unroll
  for(int i=0;i<44;i++) Mp[i]=0.f;
  int es = t>>4, ec = t&15;
  const float* s2p = &s2[(size_t)(b0+es)*H_ + k0];

  #pragma unroll
  for(int ph=0; ph<2; ph++){
    __syncthreads();
    if((wv>>1) == ph){
      int w1b = wv & 1;
      #pragma unroll
      for(int mt=0; mt<9; mt++){
        #pragma unroll
        for(int n2=0;n2<2;n2++){
          int col = (2*w1b+n2)*16 + fr_m;
          int rowb = mt*16 + fr_q*4;
          #pragma unroll
          for(int rg=0;rg<4;rg++)
            sm.Td[col*LDT + rowb + rg] = acc[mt][n2][rg];
        }
      }
    }
    __syncthreads();
    float4 s2v = *(const float4*)&s2p[ph*64 + ec*4];
    float4 w3v = *(const float4*)&W3[k0 + ph*64 + ec*4];
    float dv[4] = { w3v.x*s2v.x*(1.f-s2v.x), w3v.y*s2v.y*(1.f-s2v.y),
                    w3v.z*s2v.z*(1.f-s2v.z), w3v.w*s2v.w*(1.f-s2v.w) };
    #pragma unroll
    for(int e=0;e<4;e++){
      int col = ec*4+e;
      const float* tp = &sm.Td[col*LDT + es*8];
      float4 t0 = *(const float4*)tp, t1 = *(const float4*)(tp+4);
      float T8[8] = {t0.x,t0.y,t0.z,t0.w,t1.x,t1.y,t1.z,t1.w};
      float vv = sm.Td[col*LDT + 128 + es];
      float d = dv[e];
      int ix=0;
      #pragma unroll
      for(int m=0;m<8;m++){
        float w = T8[m]*d;
        Mp[36+m] += w*vv;
        #pragma unroll
        for(int n=m;n<8;n++){ Mp[ix] += w*T8[n]; ix++; }
      }
    }
  }
  // reduce over the 16 column-group lanes
  #pragma unroll
  for(int i=0;i<44;i++){
    #pragma unroll
    for(int off=1; off<16; off<<=1) Mp[i] += __shfl_xor(Mp[i], off, 64);
  }
  if(ec==0){
    float* o = &Mpart[((size_t)(b0+es)*8 + kb)*44];
    #pragma unroll
    for(int i=0;i<44;i++) o[i] = Mp[i];
  }
}

// ---------------- K6: assemble + f64 solve ----------------
__global__ __launch_bounds__(64) void k6(const float* __restrict__ x,
                    const float* __restrict__ Hz1M, const float* __restrict__ Mpart,
                    const float* __restrict__ dq16, float* __restrict__ out){
  __shared__ double A[64][73];
  int t = threadIdx.x;
  int b = blockIdx.x*64 + t;
  double* Ar = A[t];
  float qd[8];
  #pragma unroll
  for(int j=0;j<8;j++) qd[j] = x[b*16 + 8 + j];
  float Ms[44];
  #pragma unroll
  for(int i=0;i<44;i++) Ms[i]=0.f;
  for(int kb=0;kb<8;kb++){
    const float* mp = &Mpart[((size_t)b*8+kb)*44];
    #pragma unroll
    for(int i=0;i<44;i++) Ms[i] += mp[i];
  }
  #pragma unroll
  for(int i=0;i<8;i++){
    #pragma unroll
    for(int j=0;j<8;j++) Ar[i*9+j] = (double)Hz1M[(size_t)b*64 + i*8 + j];
    Ar[i*9+8] = (double)dq16[b*16+i] - (double)dq16[b*16+8+i] - (double)Ms[36+i];
  }
  { int ix=0;
    for(int m=0;m<8;m++)
      for(int n=m;n<8;n++){
        Ar[m*9+n] += (double)Ms[ix];
        if(n>m) Ar[n*9+m] += (double)Ms[ix];
        ix++;
      }
  }
  for(int c=0;c<8;c++){
    int piv = c; double best = fabs(Ar[c*9+c]);
    for(int rr=c+1; rr<8; rr++){ double v = fabs(Ar[rr*9+c]); if(v>best){best=v;piv=rr;} }
    if(piv!=c){
      for(int cc=c; cc<9; cc++){ double tmp=Ar[c*9+cc]; Ar[c*9+cc]=Ar[piv*9+cc]; Ar[piv*9+cc]=tmp; }
    }
    double inv = 1.0/Ar[c*9+c];
    for(int rr=c+1; rr<8; rr++){
      double f = Ar[rr*9+c]*inv;
      for(int cc=c+1; cc<9; cc++) Ar[rr*9+cc] -= f*Ar[c*9+cc];
    }
  }
  double sol[8];
  #pragma unroll
  for(int i=7;i>=0;i--){
    double s = Ar[i*9+8];
    #pragma unroll
    for(int j=i+1;j<8;j++) s -= Ar[i*9+j]*sol[j];
    sol[i] = s/Ar[i*9+i];
  }
  #pragma unroll
  for(int j=0;j<8;j++) out[b*16+j] = qd[j];
  #pragma unroll
  for(int i=0;i<8;i++) out[b*16+8+i] = (float)sol[i];
}

extern "C" void kernel_launch(void* const* d_in, const int* in_sizes, int n_in,
                              void* d_out, int out_size, void* d_ws, size_t ws_size,
                              hipStream_t stream){
  const float* x  = (const float*)d_in[0];
  const float* W1 = (const float*)d_in[1];
  const float* b1 = (const float*)d_in[2];
  const float* W2 = (const float*)d_in[3];
  const float* b2 = (const float*)d_in[4];
  const float* W3 = (const float*)d_in[5];
  float* out = (float*)d_out;

  float* ws   = (float*)d_ws;
  size_t BH   = (size_t)B_*H_;
  float* s1   = ws;                           // B*H
  float* s2   = s1  + BH;                     // B*H
  float* u    = s2  + BH;                     // B*H  (later: Mpart + W2T planes)
  float* F64  = u   + BH;                     // H*64
  float* Hz1M = F64 + (size_t)H_*64;          // B*64
  float* dq16 = Hz1M+ (size_t)B_*64;          // B*16

  // aliases inside u's 32 MB (u is dead after k5a/k5b):
  float* Mpart = u;                                        // B*8*44 fp32 = 11.5 MB
  unsigned short* W2Th = (unsigned short*)(u + 3145728);   // 12 MB offset, 2 MB
  unsigned short* W2Tm = W2Th + (size_t)H_*H_;             // 2 MB
  unsigned short* W2Tl = W2Tm + (size_t)H_*H_;             // 2 MB

  k1_s1 <<<dim3(B_),      dim3(256), 0, stream>>>(x, W1, b1, s1);
  k2_s2 <<<dim3(64,8),    dim3(256), 0, stream>>>(s1, W2, b2, s2);
  k3_u  <<<dim3(64,8),    dim3(256), 0, stream>>>(s2, W2, W3, u);
  kF    <<<dim3(256),     dim3(256), 0, stream>>>(W1, F64);
  k5a   <<<dim3(128),     dim3(256), 0, stream>>>(s1, u, F64, Hz1M);
  k5b   <<<dim3(2048),    dim3(256), 0, stream>>>(s1, u, W1, x, dq16);
  kW2T  <<<dim3(32,8),    dim3(256), 0, stream>>>(W2, W2Th, W2Tm, W2Tl);
  k4_mfma<<<dim3(4096),   dim3(256), 0, stream>>>(s1, s2, x, W1, W2Th, W2Tm, W2Tl, W3, Mpart);
  k6    <<<dim3(128),     dim3(64),  0, stream>>>(x, Hz1M, Mpart, dq16, out);
}